// Round 1
// baseline (291.876 us; speedup 1.0000x reference)
//
#include <hip/hip_runtime.h>
#include <cstddef>

// Problem dims (fixed by setup_inputs)
#define Mdim 256     // batch B
#define Ndim 2048    // neurons N
#define Kdim 2048    // K (= N, W is NxN)
#define Tsteps 128   // time steps

typedef float v4f __attribute__((ext_vector_type(4)));

// ---------------------------------------------------------------------------
// Kernel 1: scan W -> 256-byte tile-nonzero bitmap in ws.
// flags byte[c*16 + g]: bit i set iff tile (kt = g*8+i, column c) nonzero.
// Grid (16 c, 16 g), 256 threads; one byte per block, single writer -> no
// init, no atomics (ws arrives poisoned).
// ---------------------------------------------------------------------------
__global__ __launch_bounds__(256) void scan_w_kernel(
    const float* __restrict__ W, unsigned char* __restrict__ flags)
{
    const int c = blockIdx.x;   // column group (n / 128)
    const int g = blockIdx.y;   // k-tile group (kt / 8)
    const int tid = threadIdx.x;

    __shared__ int wmask[4];

    const int coff = (tid & 31) * 4;       // 0..124
    const int rbase = tid >> 5;            // 0..7

    unsigned mask = 0;
#pragma unroll
    for (int it = 0; it < 16; ++it) {
        const int r = it * 8 + rbase;      // 0..127, tile bit = it>>1
        const float4 v = *(const float4*)&W[(size_t)(g * 128 + r) * Ndim + c * 128 + coff];
        const bool nz = (v.x != 0.0f) | (v.y != 0.0f) | (v.z != 0.0f) | (v.w != 0.0f);
        mask |= (nz ? 1u : 0u) << (it >> 1);
    }
#pragma unroll
    for (int off = 32; off; off >>= 1) mask |= __shfl_down(mask, off);
    if ((tid & 63) == 0) wmask[tid >> 6] = (int)mask;
    __syncthreads();
    if (tid == 0) {
        const int m = wmask[0] | wmask[1] | wmask[2] | wmask[3];
        flags[c * 16 + g] = (unsigned char)m;
    }
}

// ---------------------------------------------------------------------------
// Kernel 2: batch-blocked current precompute  I = x @ W  -> ws (+4 KB).
// Each block: 4 batch rows x 512 columns. Reusing every W load across 4 rows
// cuts W traffic 268 MB -> 67 MB vs. computing I inside the rollout kernel
// (which re-read the flagged band once per batch row).
// Wave spans exactly one 128-col flag group (64 lanes * 2 cols) -> the
// while(word) loop is wave-uniform, no divergence.
// Accumulation order over flagged tiles (ascending kt, fmaf chain) is
// IDENTICAL to the previous fused kernel -> I is bit-identical.
// ---------------------------------------------------------------------------
__global__ __launch_bounds__(256, 2) void current_kernel(
    const float* __restrict__ x, const float* __restrict__ W,
    const unsigned* __restrict__ flags, float* __restrict__ I)
{
    const int tid = threadIdx.x;
    const int r0 = blockIdx.x * 4;              // batch row group (4 rows)
    const int n0 = blockIdx.y * 512;            // column group (512 cols)
    const int n = n0 + tid * 2;
    const int c = n >> 7;                       // flag column (wave-uniform)

    __shared__ float xs[4][Kdim];               // 32 KB: 4 x-rows

    {
        const float* xp = x + (size_t)r0 * Kdim;
#pragma unroll
        for (int r = 0; r < 4; ++r) {
            *(float4*)&xs[r][tid * 4]        = *(const float4*)&xp[(size_t)r * Kdim + tid * 4];
            *(float4*)&xs[r][1024 + tid * 4] = *(const float4*)&xp[(size_t)r * Kdim + 1024 + tid * 4];
        }
    }
    __syncthreads();

    float acc[4][2] = {{0.0f, 0.0f}, {0.0f, 0.0f}, {0.0f, 0.0f}, {0.0f, 0.0f}};
#pragma unroll
    for (int w = 0; w < 4; ++w) {
        unsigned word = flags[c * 4 + w];       // bits kt = w*32 + bit
        while (word) {
            const int bit = __builtin_ctz(word);
            word &= word - 1;
            const int k0 = (w * 32 + bit) * 16;
            const float* wp = W + (size_t)k0 * Ndim + n;
#pragma unroll
            for (int kk = 0; kk < 16; ++kk) {
                const float2 wv = *(const float2*)(wp + (size_t)kk * Ndim);
#pragma unroll
                for (int r = 0; r < 4; ++r) {
                    const float xv = xs[r][k0 + kk];         // LDS broadcast
                    acc[r][0] = fmaf(xv, wv.x, acc[r][0]);
                    acc[r][1] = fmaf(xv, wv.y, acc[r][1]);
                }
            }
        }
    }
#pragma unroll
    for (int r = 0; r < 4; ++r)
        *(float2*)&I[(size_t)(r0 + r) * Ndim + n] = *(const float2*)acc[r];
}

// ---------------------------------------------------------------------------
// Kernel 3: LIF rollout. Loads its 16 B of I, runs the 128-step recurrence
// packing spikes into 16 u32 regs (proven R6 structure), then streams out.
// Phase B trimmed to 6 ops/elem/step: the (1-Z_prev) multiply is replaced by
// a delayed-reset cndmask  V_t = Z_{t-1} ? 0 : (ALPHA*V + I), which is
// bit-equivalent for the spike outputs (only the sign of the post-spike zero
// differs; ALPHA*(-0)+I == ALPHA*(+0)+I for every comparison-visible path).
// __fmul_rn/__fadd_rn forbid FMA contraction -> bit-match numpy's mul+add.
// Phase C: natural-order streaming write of 268 MB, all stores independent
// (fire-and-forget nontemporal) -> HBM-write-BW-bound (~42 us).
// ---------------------------------------------------------------------------
__global__ __launch_bounds__(256, 2) void lif_kernel(
    const float* __restrict__ I, float* __restrict__ out)
{
    const int tid = threadIdx.x;
    const int b = blockIdx.x >> 1;                        // uniform per block
    const int n = ((blockIdx.x & 1) << 10) + tid * 4;     // 0..2047

    const float4 iv4 = *(const float4*)&I[(size_t)b * Ndim + n];
    const float Iv[4] = {iv4.x, iv4.y, iv4.z, iv4.w};

    // fp32(exp(-0.1) computed in f64) — matches numpy scalar promotion
    const float ALPHA = (float)0.9048374180359595;

    // ---- Phase B: recurrence, pack spikes into bits (no stores) ----
    unsigned zb[4][4] = {{0u, 0u, 0u, 0u}, {0u, 0u, 0u, 0u},
                         {0u, 0u, 0u, 0u}, {0u, 0u, 0u, 0u}};
    float V[4] = {0.0f, 0.0f, 0.0f, 0.0f};
    bool Zp[4] = {false, false, false, false};
#pragma unroll
    for (int w = 0; w < 4; ++w) {
#pragma unroll
        for (int t2 = 0; t2 < 32; ++t2) {
#pragma unroll
            for (int j = 0; j < 4; ++j) {
                const float u = __fadd_rn(__fmul_rn(ALPHA, V[j]), Iv[j]); // ALPHA*V + I
                const float v = Zp[j] ? 0.0f : u;          // delayed reset (prev spike)
                V[j] = v;
                const bool sp = (v >= 1.0f);
                zb[j][w] |= sp ? (1u << t2) : 0u;
                Zp[j] = sp;
            }
        }
    }

    // ---- Phase C: natural-order streaming write (all stores independent) ----
    float* op = out + (size_t)b * Tsteps * Ndim + n;
#pragma unroll
    for (int w = 0; w < 4; ++w) {
#pragma unroll
        for (int t2 = 0; t2 < 32; ++t2) {
            v4f s = { (float)((zb[0][w] >> t2) & 1u),
                      (float)((zb[1][w] >> t2) & 1u),
                      (float)((zb[2][w] >> t2) & 1u),
                      (float)((zb[3][w] >> t2) & 1u) };
            __builtin_nontemporal_store(s, (v4f*)(op + (size_t)(w * 32 + t2) * Ndim));
        }
    }
}

// ---------------------------------------------------------------------------
extern "C" void kernel_launch(void* const* d_in, const int* in_sizes, int n_in,
                              void* d_out, int out_size, void* d_ws, size_t ws_size,
                              hipStream_t stream) {
    const float* x = (const float*)d_in[0];   // [256, 2048] fp32
    const float* W = (const float*)d_in[1];   // [2048, 2048] fp32
    float* out = (float*)d_out;               // [256, 128, 2048] fp32

    unsigned char* flags = (unsigned char*)d_ws;          // 256 B @ ws+0
    float* Ibuf = (float*)((char*)d_ws + 4096);           // 2 MB  @ ws+4KB

    scan_w_kernel<<<dim3(16, 16), 256, 0, stream>>>(W, flags);

    current_kernel<<<dim3(Mdim / 4, Ndim / 512), 256, 0, stream>>>(
        x, W, (const unsigned*)flags, Ibuf);

    const int sim_blocks = Mdim * Ndim / 1024;            // 512
    lif_kernel<<<dim3(sim_blocks), 256, 0, stream>>>(Ibuf, out);
}

// Round 3
// 285.714 us; speedup vs baseline: 1.0216x; 1.0216x over previous
//
#include <hip/hip_runtime.h>
#include <cstddef>

// Problem dims (fixed by setup_inputs)
#define Mdim 256     // batch B
#define Ndim 2048    // neurons N
#define Kdim 2048    // K (= N, W is NxN)
#define Tsteps 128   // time steps

typedef float v4f __attribute__((ext_vector_type(4)));

// ---------------------------------------------------------------------------
// Kernel 1: scan W -> ws.
//   flags[0..255]   : tile-nonzero bitmap. byte[c*16+g] bit i set iff tile
//                     (kt = g*8+i, column-group c) nonzero.
//   flags[256..511] : per-block EXACT-IDENTITY verdict (0xFF iff this 128x128
//                     region of W equals eye(N) restricted to it).
// Grid (16 c, 16 g), 256 threads; one flag byte + one verdict byte per block,
// single writer -> no init, no atomics (ws arrives poisoned).
// Coherence: ws is consumed by the NEXT dispatch -> kernel-boundary cache
// maintenance makes it visible (proven in R0/R1; in-kernel grid.sync was NOT
// sufficient across XCD L2s -> R2 failure).
// ---------------------------------------------------------------------------
__global__ __launch_bounds__(256) void scan_w_kernel(
    const float* __restrict__ W, unsigned char* __restrict__ flags)
{
    const int c = blockIdx.x;   // column group (n / 128)
    const int g = blockIdx.y;   // k-tile group (kt / 8)
    const int tid = threadIdx.x;

    __shared__ int wmask[4];
    __shared__ int imask[4];

    const int coff = (tid & 31) * 4;       // 0..124
    const int rbase = tid >> 5;            // 0..7

    unsigned mask = 0;
    unsigned ident = 1u;
#pragma unroll
    for (int it = 0; it < 16; ++it) {
        const int r = it * 8 + rbase;      // 0..127, tile bit = it>>1
        const int grow = g * 128 + r;      // global row
        const int gc0 = c * 128 + coff;    // global col of .x
        const float4 v = *(const float4*)&W[(size_t)grow * Ndim + gc0];
        const bool nz = (v.x != 0.0f) | (v.y != 0.0f) | (v.z != 0.0f) | (v.w != 0.0f);
        mask |= (nz ? 1u : 0u) << (it >> 1);
        // exact-identity check for this region of eye(N)
        const float e0 = (grow == gc0 + 0) ? 1.0f : 0.0f;
        const float e1 = (grow == gc0 + 1) ? 1.0f : 0.0f;
        const float e2 = (grow == gc0 + 2) ? 1.0f : 0.0f;
        const float e3 = (grow == gc0 + 3) ? 1.0f : 0.0f;
        ident &= ((v.x == e0) && (v.y == e1) && (v.z == e2) && (v.w == e3)) ? 1u : 0u;
    }
#pragma unroll
    for (int off = 32; off; off >>= 1) {
        mask |= __shfl_down(mask, off);
        ident &= __shfl_down(ident, off);
    }
    if ((tid & 63) == 0) { wmask[tid >> 6] = (int)mask; imask[tid >> 6] = (int)ident; }
    __syncthreads();
    if (tid == 0) {
        flags[c * 16 + g] = (unsigned char)(wmask[0] | wmask[1] | wmask[2] | wmask[3]);
        flags[256 + c * 16 + g] =
            (imask[0] & imask[1] & imask[2] & imask[3]) ? (unsigned char)0xFF
                                                        : (unsigned char)0x00;
    }
}

// ---------------------------------------------------------------------------
// Kernel 2: fused current + LIF rollout + streaming write.
// Identity fast path: if ALL 256 verdict bytes are 0xFF, W == eye(N) exactly,
//   so I[b,n] = x[b,n] BIT-EXACTLY (the proven fmaf chain over the diagonal
//   tiles sums one x[n]*1.0 with exact zeros) -> skip LDS staging and the
//   entire Phase A; one float4 load replaces the W-band traversal.
// General path: unchanged proven R0 structure (LDS x-row + flagged-tile dot,
//   ascending kt, identical fmaf chain).
// Phase B+C interleaved per step: compute Z_t (5 VALU/elem: mul, add,
//   delayed-reset cndmask (verified bit-exact R1), cmp, cndmask), then fire
//   the nontemporal dwordx4 immediately. Stores drain under the recurrence
//   -> the kernel is paced by the 268 MB HBM write stream (~43 us floor).
// __fmul_rn/__fadd_rn forbid FMA contraction -> bit-match numpy's mul+add.
// ---------------------------------------------------------------------------
__global__ __launch_bounds__(256, 2) void lif_fused_kernel(
    const float* __restrict__ x, const float* __restrict__ W,
    const unsigned* __restrict__ flags, float* __restrict__ out)
{
    __shared__ float xs[Kdim];   // 8 KB: this block's x row (general path)

    const int tid = threadIdx.x;
    const int b = blockIdx.x >> 1;                        // uniform per block
    const int n = ((blockIdx.x & 1) << 10) + tid * 4;     // 0..2047
    const int c = n >> 7;                                 // flag column

    // identity verdict: AND of the 64 verdict words (bytes 256..511)
    unsigned idv = flags[64 + (tid & 63)];
#pragma unroll
    for (int off = 32; off; off >>= 1) idv &= __shfl_down(idv, off);
    idv = __shfl(idv, 0);                 // wave-uniform; same in all 4 waves
    const bool ident = (idv == 0xFFFFFFFFu);   // block-uniform branch

    float Iv[4];
    if (ident) {
        // W == eye -> I = x, bit-identical to the fmaf chain
        const float4 iv4 = *(const float4*)&x[(size_t)b * Kdim + n];
        Iv[0] = iv4.x; Iv[1] = iv4.y; Iv[2] = iv4.z; Iv[3] = iv4.w;
    } else {
        // ---- stage x[b,:] -> LDS ----
        const float* xp = x + (size_t)b * Kdim;
        *(float4*)&xs[tid * 4]        = *(const float4*)&xp[tid * 4];
        *(float4*)&xs[1024 + tid * 4] = *(const float4*)&xp[1024 + tid * 4];
        __syncthreads();                  // block-uniform path: legal

        // ---- Phase A: dot over flagged k-tiles, ascending kt ----
        float f0 = 0.0f, f1 = 0.0f, f2 = 0.0f, f3 = 0.0f;
#pragma unroll
        for (int w = 0; w < 4; ++w) {
            unsigned word = flags[c * 4 + w];   // bits kt = w*32 + bit
            while (word) {
                const int bit = __builtin_ctz(word);
                word &= word - 1;
                const int k0 = (w * 32 + bit) * 16;
                const float* wp = W + (size_t)k0 * Ndim + n;
#pragma unroll
                for (int kk = 0; kk < 16; ++kk) {
                    const float xv = xs[k0 + kk];                    // LDS broadcast
                    const float4 wv = *(const float4*)(wp + (size_t)kk * Ndim);
                    f0 = fmaf(xv, wv.x, f0);
                    f1 = fmaf(xv, wv.y, f1);
                    f2 = fmaf(xv, wv.z, f2);
                    f3 = fmaf(xv, wv.w, f3);
                }
            }
        }
        Iv[0] = f0; Iv[1] = f1; Iv[2] = f2; Iv[3] = f3;
    }

    // fp32(exp(-0.1) computed in f64) — matches numpy scalar promotion
    const float ALPHA = (float)0.9048374180359595;

    // ---- Phase B+C interleaved: compute step t, store step t immediately ----
    float V[4]  = {0.0f, 0.0f, 0.0f, 0.0f};
    float Zf[4] = {0.0f, 0.0f, 0.0f, 0.0f};
    float* op = out + (size_t)b * Tsteps * Ndim + n;
#pragma unroll
    for (int t = 0; t < Tsteps; ++t) {
#pragma unroll
        for (int j = 0; j < 4; ++j) {
            const float u = __fadd_rn(__fmul_rn(ALPHA, V[j]), Iv[j]); // ALPHA*V + I
            const float v = (Zf[j] != 0.0f) ? 0.0f : u;   // delayed reset (prev spike)
            V[j] = v;
            Zf[j] = (v >= 1.0f) ? 1.0f : 0.0f;
        }
        v4f s = {Zf[0], Zf[1], Zf[2], Zf[3]};
        __builtin_nontemporal_store(s, (v4f*)(op + (size_t)t * Ndim));
    }
}

// ---------------------------------------------------------------------------
extern "C" void kernel_launch(void* const* d_in, const int* in_sizes, int n_in,
                              void* d_out, int out_size, void* d_ws, size_t ws_size,
                              hipStream_t stream) {
    const float* x = (const float*)d_in[0];   // [256, 2048] fp32
    const float* W = (const float*)d_in[1];   // [2048, 2048] fp32
    float* out = (float*)d_out;               // [256, 128, 2048] fp32

    unsigned char* flags = (unsigned char*)d_ws;   // 512 bytes used

    scan_w_kernel<<<dim3(16, 16), 256, 0, stream>>>(W, flags);

    const int sim_blocks = Mdim * Ndim / 1024;     // 512
    lif_fused_kernel<<<dim3(sim_blocks), 256, 0, stream>>>(
        x, W, (const unsigned*)flags, out);
}

// Round 4
// 283.954 us; speedup vs baseline: 1.0279x; 1.0062x over previous
//
#include <hip/hip_runtime.h>
#include <cstddef>

// Problem dims (fixed by setup_inputs)
#define Mdim 256     // batch B
#define Ndim 2048    // neurons N
#define Kdim 2048    // K (= N, W is NxN)
#define Tsteps 128   // time steps

typedef float v4f __attribute__((ext_vector_type(4)));

// ---------------------------------------------------------------------------
// Kernel 1: scan W -> ws.
//   flags[0..255]   : tile-nonzero bitmap. byte[c*16+g] bit i set iff tile
//                     (kt = g*8+i, column-group c) nonzero.
//   flags[256..511] : per-block EXACT-IDENTITY verdict (0xFF iff this 128x128
//                     region of W equals eye(N) restricted to it).
// Grid (16 c, 16 g), 256 threads; one flag byte + one verdict byte per block,
// single writer -> no init, no atomics (ws arrives poisoned).
// Coherence: ws is consumed by the NEXT dispatch -> kernel-boundary cache
// maintenance makes it visible (proven R0/R1/R3; in-kernel grid.sync was NOT
// sufficient across XCD L2s -> R2 failure).
// ---------------------------------------------------------------------------
__global__ __launch_bounds__(256) void scan_w_kernel(
    const float* __restrict__ W, unsigned char* __restrict__ flags)
{
    const int c = blockIdx.x;   // column group (n / 128)
    const int g = blockIdx.y;   // k-tile group (kt / 8)
    const int tid = threadIdx.x;

    __shared__ int wmask[4];
    __shared__ int imask[4];

    const int coff = (tid & 31) * 4;       // 0..124
    const int rbase = tid >> 5;            // 0..7

    unsigned mask = 0;
    unsigned ident = 1u;
#pragma unroll
    for (int it = 0; it < 16; ++it) {
        const int r = it * 8 + rbase;      // 0..127, tile bit = it>>1
        const int grow = g * 128 + r;      // global row
        const int gc0 = c * 128 + coff;    // global col of .x
        const float4 v = *(const float4*)&W[(size_t)grow * Ndim + gc0];
        const bool nz = (v.x != 0.0f) | (v.y != 0.0f) | (v.z != 0.0f) | (v.w != 0.0f);
        mask |= (nz ? 1u : 0u) << (it >> 1);
        // exact-identity check for this region of eye(N)
        const float e0 = (grow == gc0 + 0) ? 1.0f : 0.0f;
        const float e1 = (grow == gc0 + 1) ? 1.0f : 0.0f;
        const float e2 = (grow == gc0 + 2) ? 1.0f : 0.0f;
        const float e3 = (grow == gc0 + 3) ? 1.0f : 0.0f;
        ident &= ((v.x == e0) && (v.y == e1) && (v.z == e2) && (v.w == e3)) ? 1u : 0u;
    }
#pragma unroll
    for (int off = 32; off; off >>= 1) {
        mask |= __shfl_down(mask, off);
        ident &= __shfl_down(ident, off);
    }
    if ((tid & 63) == 0) { wmask[tid >> 6] = (int)mask; imask[tid >> 6] = (int)ident; }
    __syncthreads();
    if (tid == 0) {
        flags[c * 16 + g] = (unsigned char)(wmask[0] | wmask[1] | wmask[2] | wmask[3]);
        flags[256 + c * 16 + g] =
            (imask[0] & imask[1] & imask[2] & imask[3]) ? (unsigned char)0xFF
                                                        : (unsigned char)0x00;
    }
}

// ---------------------------------------------------------------------------
// Kernel 2: fused current + LIF rollout + streaming write, T-SPLIT PROBE.
// Grid 1024 = (b, column-half, T-half); __launch_bounds__(256,4) -> 4
// blocks/CU co-resident (16 waves/CU), 2x the write-phase MLP of R3.
// Every block runs the FULL 128-step recurrence in registers (values bit-
// identical; the redundant 64 no-store steps cost ~1 us VALU, hidden under
// the write stream) but stores only its own 64-step half.
// Identity fast path: if all 256 verdict bytes are 0xFF, W == eye exactly ->
//   I = x bit-exactly (verified R3). General path = proven R0 flagged-tile
//   dot (ascending kt, identical fmaf chain).
// Recurrence (verified bit-exact R1/R3): delayed-reset cndmask,
//   V_t = Z_{t-1} ? 0 : (ALPHA*V + I);  __fmul_rn/__fadd_rn forbid FMA
//   contraction -> bit-match numpy's mul+add.
// ---------------------------------------------------------------------------
__global__ __launch_bounds__(256, 4) void lif_fused_kernel(
    const float* __restrict__ x, const float* __restrict__ W,
    const unsigned* __restrict__ flags, float* __restrict__ out)
{
    __shared__ float xs[Kdim];   // 8 KB: this block's x row (general path)

    const int tid = threadIdx.x;
    const int b  = blockIdx.x >> 2;                       // 0..255
    const int n  = (((blockIdx.x >> 1) & 1) << 10) + tid * 4;  // 0..2047
    const int th = blockIdx.x & 1;                        // T-half (stores only)
    const int c  = n >> 7;                                // flag column

    // identity verdict: AND of the 64 verdict words (bytes 256..511)
    unsigned idv = flags[64 + (tid & 63)];
#pragma unroll
    for (int off = 32; off; off >>= 1) idv &= __shfl_down(idv, off);
    idv = __shfl(idv, 0);                 // wave-uniform; same in all 4 waves
    const bool ident = (idv == 0xFFFFFFFFu);   // block-uniform branch

    float Iv[4];
    if (ident) {
        // W == eye -> I = x, bit-identical to the fmaf chain
        const float4 iv4 = *(const float4*)&x[(size_t)b * Kdim + n];
        Iv[0] = iv4.x; Iv[1] = iv4.y; Iv[2] = iv4.z; Iv[3] = iv4.w;
    } else {
        // ---- stage x[b,:] -> LDS ----
        const float* xp = x + (size_t)b * Kdim;
        *(float4*)&xs[tid * 4]        = *(const float4*)&xp[tid * 4];
        *(float4*)&xs[1024 + tid * 4] = *(const float4*)&xp[1024 + tid * 4];
        __syncthreads();                  // block-uniform path: legal

        // ---- Phase A: dot over flagged k-tiles, ascending kt ----
        float f0 = 0.0f, f1 = 0.0f, f2 = 0.0f, f3 = 0.0f;
#pragma unroll
        for (int w = 0; w < 4; ++w) {
            unsigned word = flags[c * 4 + w];   // bits kt = w*32 + bit
            while (word) {
                const int bit = __builtin_ctz(word);
                word &= word - 1;
                const int k0 = (w * 32 + bit) * 16;
                const float* wp = W + (size_t)k0 * Ndim + n;
#pragma unroll
                for (int kk = 0; kk < 16; ++kk) {
                    const float xv = xs[k0 + kk];                    // LDS broadcast
                    const float4 wv = *(const float4*)(wp + (size_t)kk * Ndim);
                    f0 = fmaf(xv, wv.x, f0);
                    f1 = fmaf(xv, wv.y, f1);
                    f2 = fmaf(xv, wv.z, f2);
                    f3 = fmaf(xv, wv.w, f3);
                }
            }
        }
        Iv[0] = f0; Iv[1] = f1; Iv[2] = f2; Iv[3] = f3;
    }

    // fp32(exp(-0.1) computed in f64) — matches numpy scalar promotion
    const float ALPHA = (float)0.9048374180359595;

    float V[4]  = {0.0f, 0.0f, 0.0f, 0.0f};
    float Zf[4] = {0.0f, 0.0f, 0.0f, 0.0f};
    float* op = out + (size_t)b * Tsteps * Ndim + n;

    // ---- steps 0..63: th==0 stores, th==1 advances state only ----
    if (th == 0) {
#pragma unroll
        for (int t = 0; t < 64; ++t) {
#pragma unroll
            for (int j = 0; j < 4; ++j) {
                const float u = __fadd_rn(__fmul_rn(ALPHA, V[j]), Iv[j]);
                const float v = (Zf[j] != 0.0f) ? 0.0f : u;
                V[j] = v;
                Zf[j] = (v >= 1.0f) ? 1.0f : 0.0f;
            }
            v4f s = {Zf[0], Zf[1], Zf[2], Zf[3]};
            __builtin_nontemporal_store(s, (v4f*)(op + (size_t)t * Ndim));
        }
        // done: this block owns only the first half
    } else {
#pragma unroll
        for (int t = 0; t < 64; ++t) {
#pragma unroll
            for (int j = 0; j < 4; ++j) {
                const float u = __fadd_rn(__fmul_rn(ALPHA, V[j]), Iv[j]);
                const float v = (Zf[j] != 0.0f) ? 0.0f : u;
                V[j] = v;
                Zf[j] = (v >= 1.0f) ? 1.0f : 0.0f;
            }
        }
        // ---- steps 64..127: store ----
#pragma unroll
        for (int t = 64; t < 128; ++t) {
#pragma unroll
            for (int j = 0; j < 4; ++j) {
                const float u = __fadd_rn(__fmul_rn(ALPHA, V[j]), Iv[j]);
                const float v = (Zf[j] != 0.0f) ? 0.0f : u;
                V[j] = v;
                Zf[j] = (v >= 1.0f) ? 1.0f : 0.0f;
            }
            v4f s = {Zf[0], Zf[1], Zf[2], Zf[3]};
            __builtin_nontemporal_store(s, (v4f*)(op + (size_t)t * Ndim));
        }
    }
}

// ---------------------------------------------------------------------------
extern "C" void kernel_launch(void* const* d_in, const int* in_sizes, int n_in,
                              void* d_out, int out_size, void* d_ws, size_t ws_size,
                              hipStream_t stream) {
    const float* x = (const float*)d_in[0];   // [256, 2048] fp32
    const float* W = (const float*)d_in[1];   // [2048, 2048] fp32
    float* out = (float*)d_out;               // [256, 128, 2048] fp32

    unsigned char* flags = (unsigned char*)d_ws;   // 512 bytes used

    scan_w_kernel<<<dim3(16, 16), 256, 0, stream>>>(W, flags);

    const int sim_blocks = Mdim * Ndim / 1024 * 2; // 1024: (b, col-half, T-half)
    lif_fused_kernel<<<dim3(sim_blocks), 256, 0, stream>>>(
        x, W, (const unsigned*)flags, out);
}